// Round 12
// baseline (172.605 us; speedup 1.0000x reference)
//
#include <hip/hip_runtime.h>
#include <math.h>

typedef __bf16 bf16;
typedef __attribute__((ext_vector_type(8))) __bf16 bf16x8;
typedef __attribute__((ext_vector_type(4))) float f32x4;

#define LOG2E 1.44269504088896f
#define SCALE 0.125f   // 1/sqrt(64)

__device__ inline f32x4 mfma16(bf16x8 a, bf16x8 b, f32x4 c) {
    return __builtin_amdgcn_mfma_f32_16x16x32_bf16(a, b, c, 0, 0, 0);
}
__device__ inline bf16x8 cvt8(float4 v0, float4 v1) {
    bf16x8 o;
    o[0] = (bf16)v0.x; o[1] = (bf16)v0.y; o[2] = (bf16)v0.z; o[3] = (bf16)v0.w;
    o[4] = (bf16)v1.x; o[5] = (bf16)v1.y; o[6] = (bf16)v1.z; o[7] = (bf16)v1.w;
    return o;
}
__device__ inline float fastexp2(float x) {
    float r;
    asm("v_exp_f32 %0, %1" : "=v"(r) : "v"(x));
    return r;
}
__device__ inline float fastrcp(float x) {
    float r;
    asm("v_rcp_f32 %0, %1" : "=v"(r) : "v"(x));
    return r;
}

// ---------------------------------------------------------- QKV GEMM --------
// 64x128 tile, reg-staged prefetch pipeline: next K-step's global loads issue
// before the MFMA cluster, hiding load latency. f32 in, cvt at LDS-store time.
__global__ __launch_bounds__(256) void gemm_qkv_kernel(
        const float* __restrict__ A, const float* __restrict__ Wq,
        const float* __restrict__ Wk, const float* __restrict__ Wv,
        const float* __restrict__ bq, const float* __restrict__ bk,
        const float* __restrict__ bv,
        bf16* __restrict__ Qb, bf16* __restrict__ Kb, bf16* __restrict__ Vt) {
    __shared__ bf16 smem[64 * 72 + 128 * 72];
    bf16 (*Asm)[72] = (bf16(*)[72])smem;
    bf16 (*Bsm)[72] = (bf16(*)[72])(smem + 64 * 72);
    int t = threadIdx.x, w = t >> 6, lane = t & 63, g = lane >> 4, lo = lane & 15;
    int rowbase = blockIdx.x * 64, colbase = blockIdx.y * 128;
    int proj = colbase >> 9, wcol = colbase & 511;
    const float* Wsrc = (proj == 0) ? Wq : (proj == 1 ? Wk : Wv);
    const float* bsrc = (proj == 0) ? bq : (proj == 1 ? bk : bv);
    int wr = (w >> 1) * 32, wc = (w & 1) * 64;
    f32x4 acc[2][4] = {};
    int arow = t >> 2, acol = (t & 3) * 16;
    int brow = t >> 1, bcol = (t & 1) * 32;
    const float* aptr = &A[(size_t)(rowbase + arow) * 512 + acol];
    const float* bptr = &Wsrc[(size_t)(wcol + brow) * 512 + bcol];
    float4 ar[4], br[8];
    {
        const float4* as = (const float4*)aptr;
        ar[0] = as[0]; ar[1] = as[1]; ar[2] = as[2]; ar[3] = as[3];
        const float4* bs = (const float4*)bptr;
        for (int q = 0; q < 8; q++) br[q] = bs[q];
    }
    for (int kb = 0; kb < 512; kb += 64) {
        __syncthreads();
        *(bf16x8*)&Asm[arow][acol]     = cvt8(ar[0], ar[1]);
        *(bf16x8*)&Asm[arow][acol + 8] = cvt8(ar[2], ar[3]);
        *(bf16x8*)&Bsm[brow][bcol]      = cvt8(br[0], br[1]);
        *(bf16x8*)&Bsm[brow][bcol + 8]  = cvt8(br[2], br[3]);
        *(bf16x8*)&Bsm[brow][bcol + 16] = cvt8(br[4], br[5]);
        *(bf16x8*)&Bsm[brow][bcol + 24] = cvt8(br[6], br[7]);
        __syncthreads();
        if (kb + 64 < 512) {
            const float4* as = (const float4*)(aptr + kb + 64);
            ar[0] = as[0]; ar[1] = as[1]; ar[2] = as[2]; ar[3] = as[3];
            const float4* bs = (const float4*)(bptr + kb + 64);
            for (int q = 0; q < 8; q++) br[q] = bs[q];
        }
        __builtin_amdgcn_s_setprio(1);
        for (int kk = 0; kk < 64; kk += 32) {
            bf16x8 af[2], bfr[4];
            for (int m = 0; m < 2; m++) af[m]  = *(const bf16x8*)&Asm[wr + 16 * m + lo][kk + 8 * g];
            for (int n = 0; n < 4; n++) bfr[n] = *(const bf16x8*)&Bsm[wc + 16 * n + lo][kk + 8 * g];
            for (int m = 0; m < 2; m++)
                for (int n = 0; n < 4; n++)
                    acc[m][n] = mfma16(af[m], bfr[n], acc[m][n]);
        }
        __builtin_amdgcn_s_setprio(0);
    }
    __syncthreads();
    bf16 (*Cl)[132] = (bf16(*)[132])smem;
    for (int n = 0; n < 4; n++) {
        float bv = bsrc[wcol + wc + 16 * n + lo];
        for (int m = 0; m < 2; m++)
            for (int r = 0; r < 4; r++)
                Cl[wr + 16 * m + 4 * g + r][wc + 16 * n + lo] = (bf16)(acc[m][n][r] + bv);
    }
    __syncthreads();
    int h0 = (colbase >> 6) & 7;
    int bidx = rowbase >> 10, i0g = rowbase & 1023;
    if (proj < 2) {
        int row = t >> 2, q4 = t & 3;
        int head = h0 + (q4 >> 1), d0 = (q4 & 1) * 32;
        bf16* dst = (proj == 0 ? Qb : Kb) +
                    ((size_t)(bidx * 8 + head) * 1024 + i0g + row) * 64 + d0;
        for (int ch = 0; ch < 4; ch++)
            *(bf16x8*)&dst[ch * 8] = *(const bf16x8*)&Cl[row][(q4 >> 1) * 64 + d0 + ch * 8];
    } else {
        int dcol = t >> 1, ihalf = t & 1;
        int head = h0 + (dcol >> 6), d = dcol & 63;
        bf16* dst = Vt + ((size_t)(bidx * 8 + head) * 64 + d) * 1024 + i0g + ihalf * 32;
        for (int ch = 0; ch < 4; ch++) {
            bf16x8 v;
            for (int q = 0; q < 8; q++) v[q] = Cl[ihalf * 32 + ch * 8 + q][dcol];
            *(bf16x8*)&dst[ch * 8] = v;
        }
    }
}

// ----------------------------------------------------- fused attention ------
// Fixed-max flash attention, KV-split=2, reg-staged prefetch pipeline.
// geo MFMA emits u = -d^2/2 (A:[s_hi,s_lo,1,1] x B:[1,1,s_hi,s_lo]).
// bias = sum_c alpha_c * e^(u/sigma_c^2), clamp u<=0. Row sums via ones-MFMA.
__global__ __launch_bounds__(256) void attn_kernel(
        const bf16* __restrict__ Qb, const bf16* __restrict__ Kb,
        const bf16* __restrict__ Vt, const float* __restrict__ x,
        const float* __restrict__ alpha, const float* __restrict__ log_sigma,
        float* __restrict__ o_part, float* __restrict__ l_part) {
    __shared__ bf16 Klds[64][72];
    __shared__ bf16 VTlds[64][72];
    __shared__ bf16 Xlds[64][80];    // comp c at cols c*24: 16 x, [1,1,s_hi,s_lo,0..]
    __shared__ bf16 Plds[4][16][72];

    int t = threadIdx.x;
    int w = t >> 6, lane = t & 63, g = lane >> 4, lo = lane & 15;
    int zz = blockIdx.z;
    int b = zz >> 1, split = zz & 1;
    int hh = blockIdx.y;
    int i0 = blockIdx.x * 64 + w * 16;

    float c1 = SCALE * LOG2E;
    float k2[3], alf[3];
    for (int c = 0; c < 3; c++) {
        float sg = fmaxf(expf(log_sigma[hh * 3 + c]), 1e-4f);
        k2[c] = LOG2E / (sg * sg);
        alf[c] = alpha[hh * 3 + c] * LOG2E;
    }

    const bf16* Qbase = Qb + ((size_t)(b * 8 + hh) * 1024 + i0) * 64;
    bf16x8 qa[2];
    qa[0] = *(const bf16x8*)&Qbase[lo * 64 + 8 * g];
    qa[1] = *(const bf16x8*)&Qbase[lo * 64 + 32 + 8 * g];

    // A-side geo fragments: g<2: bf16(x); g==2: [s_hi,s_lo,1,1,0..]; g==3: 0
    bf16x8 xqa[3];
    for (int c = 0; c < 3; c++) {
        bf16x8 v = {};
        if (g < 2) {
            const float4* xs = (const float4*)&x[((size_t)(b << 10) + i0 + lo) * 48 + c * 16 + 8 * g];
            v = cvt8(xs[0], xs[1]);
        } else if (g == 2) {
            const float* xr = &x[((size_t)(b << 10) + i0 + lo) * 48 + c * 16];
            float s = 0.0f;
            for (int k = 0; k < 16; k++) {
                float vv = (float)(bf16)xr[k];
                s += vv * vv;
            }
            s = -0.5f * s;
            bf16 sh = (bf16)s;
            v[0] = sh;
            v[1] = (bf16)(s - (float)sh);
            v[2] = (bf16)1.0f;
            v[3] = (bf16)1.0f;
        }
        xqa[c] = v;
    }

    bf16x8 ones;
    for (int e = 0; e < 8; e++) ones[e] = (bf16)1.0f;
    f32x4 o[4] = {};
    f32x4 lacc = {};

    // zero the pad cols 72..79 once (g==3 B-reads for c==2 land here)
    for (int idx = t; idx < 64; idx += 256)
        *(uint4*)&Xlds[idx][72] = (uint4){0, 0, 0, 0};

    int sr = t >> 2, sc = (t & 3) * 16;
    int xr = t / 3, xc = t - xr * 3;                 // staging role for t<192
    const bf16* Kbase0 = Kb + (size_t)(b * 8 + hh) * 1024 * 64;
    const bf16* Vbase  = Vt + (size_t)(b * 8 + hh) * 64 * 1024;
    int jb = split * 512;

    // prefetch regs for first tile
    bf16x8 pk0, pk1, pv0, pv1;
    float4 pxs[4];
    {
        const bf16* Kp = Kbase0 + (size_t)jb * 64;
        pk0 = *(const bf16x8*)&Kp[sr * 64 + sc];
        pk1 = *(const bf16x8*)&Kp[sr * 64 + sc + 8];
        pv0 = *(const bf16x8*)&Vbase[sr * 1024 + jb + sc];
        pv1 = *(const bf16x8*)&Vbase[sr * 1024 + jb + sc + 8];
        if (t < 192) {
            const float4* xs = (const float4*)&x[((size_t)(b << 10) + jb + xr) * 48 + xc * 16];
            for (int q = 0; q < 4; q++) pxs[q] = xs[q];
        }
    }

    for (int j0 = jb; j0 < jb + 512; j0 += 64) {
        __syncthreads();   // prev tile reads done (covers pad-zero on iter 0)
        *(bf16x8*)&Klds[sr][sc]      = pk0;
        *(bf16x8*)&Klds[sr][sc + 8]  = pk1;
        *(bf16x8*)&VTlds[sr][sc]     = pv0;
        *(bf16x8*)&VTlds[sr][sc + 8] = pv1;
        if (t < 192) {
            bf16x8 d0 = cvt8(pxs[0], pxs[1]);
            bf16x8 d1 = cvt8(pxs[2], pxs[3]);
            *(bf16x8*)&Xlds[xr][xc * 24]     = d0;
            *(bf16x8*)&Xlds[xr][xc * 24 + 8] = d1;
            float s = 0.0f;
            for (int k = 0; k < 8; k++) {
                float a0 = (float)d0[k], a1 = (float)d1[k];
                s += a0 * a0 + a1 * a1;
            }
            s = -0.5f * s;
            bf16 sh = (bf16)s;
            bf16x8 cst = {};
            cst[0] = (bf16)1.0f;             // pairs with A slot s_hi
            cst[1] = (bf16)1.0f;             // pairs with A slot s_lo
            cst[2] = sh;                     // pairs with A slot 1
            cst[3] = (bf16)(s - (float)sh);  // pairs with A slot 1
            *(bf16x8*)&Xlds[xr][xc * 24 + 16] = cst;
        }
        __syncthreads();
        if (j0 + 64 < jb + 512) {
            int jn = j0 + 64;
            const bf16* Kp = Kbase0 + (size_t)jn * 64;
            pk0 = *(const bf16x8*)&Kp[sr * 64 + sc];
            pk1 = *(const bf16x8*)&Kp[sr * 64 + sc + 8];
            pv0 = *(const bf16x8*)&Vbase[sr * 1024 + jn + sc];
            pv1 = *(const bf16x8*)&Vbase[sr * 1024 + jn + sc + 8];
            if (t < 192) {
                const float4* xs = (const float4*)&x[((size_t)(b << 10) + jn + xr) * 48 + xc * 16];
                for (int q = 0; q < 4; q++) pxs[q] = xs[q];
            }
        }

        for (int tt = 0; tt < 4; tt++) {
            f32x4 acc = {};
            bf16x8 kb0 = *(const bf16x8*)&Klds[16 * tt + lo][8 * g];
            bf16x8 kb1 = *(const bf16x8*)&Klds[16 * tt + lo][32 + 8 * g];
            __builtin_amdgcn_s_setprio(1);
            acc = mfma16(qa[0], kb0, acc);
            acc = mfma16(qa[1], kb1, acc);
            f32x4 z0 = {}, z1 = {}, z2 = {};
            f32x4 e0 = mfma16(xqa[0], *(const bf16x8*)&Xlds[16 * tt + lo][8 * g], z0);
            f32x4 e1 = mfma16(xqa[1], *(const bf16x8*)&Xlds[16 * tt + lo][24 + 8 * g], z1);
            f32x4 e2 = mfma16(xqa[2], *(const bf16x8*)&Xlds[16 * tt + lo][48 + 8 * g], z2);
            __builtin_amdgcn_s_setprio(0);
            for (int r = 0; r < 4; r++) {
                float t0 = alf[0] * fastexp2(k2[0] * fminf(e0[r], 0.0f));
                t0 = fmaf(alf[1], fastexp2(k2[1] * fminf(e1[r], 0.0f)), t0);
                t0 = fmaf(alf[2], fastexp2(k2[2] * fminf(e2[r], 0.0f)), t0);
                float p = fastexp2(fmaf(acc[r], c1, t0));
                Plds[w][4 * g + r][16 * tt + lo] = (bf16)p;
            }
        }

        bf16x8 pa0 = *(const bf16x8*)&Plds[w][lo][8 * g];
        bf16x8 pa1 = *(const bf16x8*)&Plds[w][lo][32 + 8 * g];
        __builtin_amdgcn_s_setprio(1);
        lacc = mfma16(pa0, ones, lacc);
        lacc = mfma16(pa1, ones, lacc);
        for (int td = 0; td < 4; td++) {
            bf16x8 vb0 = *(const bf16x8*)&VTlds[16 * td + lo][8 * g];
            bf16x8 vb1 = *(const bf16x8*)&VTlds[16 * td + lo][32 + 8 * g];
            o[td] = mfma16(pa0, vb0, o[td]);
            o[td] = mfma16(pa1, vb1, o[td]);
        }
        __builtin_amdgcn_s_setprio(0);
    }

    for (int td = 0; td < 4; td++)
        for (int r = 0; r < 4; r++) {
            size_t rowg = (size_t)(b * 8 + hh) * 1024 + i0 + 4 * g + r;
            o_part[((size_t)split * 32768 + rowg) * 64 + 16 * td + lo] = o[td][r];
        }
    if (lo == 0)
        for (int r = 0; r < 4; r++) {
            size_t rowg = (size_t)(b * 8 + hh) * 1024 + i0 + 4 * g + r;
            l_part[(size_t)split * 32768 + rowg] = lacc[r];
        }
}

// ------------------------------------------- output GEMM + fused merge ------
// 64x64 tile, reg-staged prefetch pipeline; merge math + v_rcp at store time.
__global__ __launch_bounds__(256) void gemm_out_kernel(
        const float* __restrict__ o_part, const float* __restrict__ l_part,
        const float* __restrict__ Wo, const float* __restrict__ bo,
        float* __restrict__ out) {
    __shared__ bf16 Asm[64][72];
    __shared__ bf16 Bsm[64][72];
    int t = threadIdx.x, w = t >> 6, lane = t & 63, g = lane >> 4, lo = lane & 15;
    int rowbase = blockIdx.x * 64, colbase = blockIdx.y * 64;
    int wr = (w >> 1) * 32, wc = (w & 1) * 32;
    f32x4 acc[2][2] = {};
    int srow = t >> 2, scol = (t & 3) * 16;
    int n0 = rowbase + srow;
    size_t rowbase_g = (size_t)((n0 >> 10) * 8) * 1024 + (n0 & 1023);

    float4 pa[4], pc[4], pb[2];
    float pl0, pl1;
    {
        size_t rowg = rowbase_g;   // hh=0
        const float4* p0 = (const float4*)&o_part[rowg * 64 + scol];
        const float4* p1 = (const float4*)&o_part[((size_t)32768 + rowg) * 64 + scol];
        for (int q = 0; q < 4; q++) { pa[q] = p0[q]; pc[q] = p1[q]; }
        pl0 = l_part[rowg]; pl1 = l_part[32768 + rowg];
        const float4* bs = (const float4*)&Wo[(size_t)(colbase + srow) * 512 + scol];
        pb[0] = bs[0]; pb[1] = bs[1];
        // note bs[2],bs[3] handled below via second pair
    }
    float4 pb2[2];
    {
        const float4* bs = (const float4*)&Wo[(size_t)(colbase + srow) * 512 + scol];
        pb2[0] = bs[2]; pb2[1] = bs[3];
    }

    for (int kb = 0; kb < 512; kb += 64) {
        __syncthreads();
        {
            float inv = fastrcp(pl0 + pl1);
            bf16x8 r0, r1;
            r0[0] = (bf16)((pa[0].x + pc[0].x) * inv); r0[1] = (bf16)((pa[0].y + pc[0].y) * inv);
            r0[2] = (bf16)((pa[0].z + pc[0].z) * inv); r0[3] = (bf16)((pa[0].w + pc[0].w) * inv);
            r0[4] = (bf16)((pa[1].x + pc[1].x) * inv); r0[5] = (bf16)((pa[1].y + pc[1].y) * inv);
            r0[6] = (bf16)((pa[1].z + pc[1].z) * inv); r0[7] = (bf16)((pa[1].w + pc[1].w) * inv);
            r1[0] = (bf16)((pa[2].x + pc[2].x) * inv); r1[1] = (bf16)((pa[2].y + pc[2].y) * inv);
            r1[2] = (bf16)((pa[2].z + pc[2].z) * inv); r1[3] = (bf16)((pa[2].w + pc[2].w) * inv);
            r1[4] = (bf16)((pa[3].x + pc[3].x) * inv); r1[5] = (bf16)((pa[3].y + pc[3].y) * inv);
            r1[6] = (bf16)((pa[3].z + pc[3].z) * inv); r1[7] = (bf16)((pa[3].w + pc[3].w) * inv);
            *(bf16x8*)&Asm[srow][scol]     = r0;
            *(bf16x8*)&Asm[srow][scol + 8] = r1;
            *(bf16x8*)&Bsm[srow][scol]     = cvt8(pb[0], pb[1]);
            *(bf16x8*)&Bsm[srow][scol + 8] = cvt8(pb2[0], pb2[1]);
        }
        __syncthreads();
        if (kb + 64 < 512) {
            int hh = (kb >> 6) + 1;
            size_t rowg = rowbase_g + (size_t)hh * 1024;
            const float4* p0 = (const float4*)&o_part[rowg * 64 + scol];
            const float4* p1 = (const float4*)&o_part[((size_t)32768 + rowg) * 64 + scol];
            for (int q = 0; q < 4; q++) { pa[q] = p0[q]; pc[q] = p1[q]; }
            pl0 = l_part[rowg]; pl1 = l_part[32768 + rowg];
            const float4* bs = (const float4*)&Wo[(size_t)(colbase + srow) * 512 + kb + 64 + scol];
            pb[0] = bs[0]; pb[1] = bs[1]; pb2[0] = bs[2]; pb2[1] = bs[3];
        }
        __builtin_amdgcn_s_setprio(1);
        for (int kk = 0; kk < 64; kk += 32) {
            bf16x8 af[2], bfr[2];
            for (int m = 0; m < 2; m++) af[m]  = *(const bf16x8*)&Asm[wr + 16 * m + lo][kk + 8 * g];
            for (int n = 0; n < 2; n++) bfr[n] = *(const bf16x8*)&Bsm[wc + 16 * n + lo][kk + 8 * g];
            for (int m = 0; m < 2; m++)
                for (int n = 0; n < 2; n++)
                    acc[m][n] = mfma16(af[m], bfr[n], acc[m][n]);
        }
        __builtin_amdgcn_s_setprio(0);
    }
    for (int n = 0; n < 2; n++) {
        int mcol = colbase + wc + 16 * n + lo;
        float bv = bo[mcol];
        for (int m = 0; m < 2; m++)
            for (int r = 0; r < 4; r++)
                out[(size_t)(rowbase + wr + 16 * m + 4 * g + r) * 512 + mcol] =
                    acc[m][n][r] + bv;
    }
}

// ---------------------------------------------------------------- launch ----
extern "C" void kernel_launch(void* const* d_in, const int* in_sizes, int n_in,
                              void* d_out, int out_size, void* d_ws, size_t ws_size,
                              hipStream_t stream) {
    const float* h  = (const float*)d_in[0];
    const float* x  = (const float*)d_in[1];
    const float* Wq = (const float*)d_in[2];
    const float* bq = (const float*)d_in[3];
    const float* Wk = (const float*)d_in[4];
    const float* bk = (const float*)d_in[5];
    const float* Wv = (const float*)d_in[6];
    const float* bv = (const float*)d_in[7];
    const float* Wo = (const float*)d_in[8];
    const float* bo = (const float*)d_in[9];
    const float* alpha     = (const float*)d_in[10];
    const float* log_sigma = (const float*)d_in[11];
    float* out = (float*)d_out;

    char* ws = (char*)d_ws;
    size_t off = 0;
    auto alloc = [&](size_t bytes) {
        char* p = ws + off;
        off += (bytes + 255) & ~(size_t)255;
        return p;
    };
    bf16*  Qb     = (bf16*)alloc((size_t)4 * 8 * 1024 * 64 * 2);
    bf16*  Kb     = (bf16*)alloc((size_t)4 * 8 * 1024 * 64 * 2);
    bf16*  Vt     = (bf16*)alloc((size_t)4 * 8 * 1024 * 64 * 2);
    float* o_part = (float*)alloc((size_t)2 * 32768 * 64 * 4);
    float* l_part = (float*)alloc((size_t)2 * 32768 * 4);

    gemm_qkv_kernel<<<dim3(64, 12), 256, 0, stream>>>(h, Wq, Wk, Wv, bq, bk, bv,
                                                      Qb, Kb, Vt);
    attn_kernel<<<dim3(16, 8, 8), 256, 0, stream>>>(
        Qb, Kb, Vt, x, alpha, log_sigma, o_part, l_part);
    gemm_out_kernel<<<dim3(64, 8), 256, 0, stream>>>(o_part, l_part, Wo, bo, out);
}